// Round 1
// 2514.469 us; speedup vs baseline: 1.3753x; 1.3753x over previous
//
#include <hip/hip_runtime.h>
#include <math.h>

namespace {
constexpr int kB = 2;
constexpr int kT = 2048;
constexpr int kD = 1024;
constexpr int kH = 16;
constexpr int kL = 8;
constexpr int kInner = 4096;
constexpr int kM = kB * kT;  // 4096 token rows
constexpr float kEps = 1e-5f;
}

typedef __attribute__((ext_vector_type(8))) short bf16x8;
typedef __attribute__((ext_vector_type(4))) float f32x4;
typedef __attribute__((ext_vector_type(16))) float f32x16;

typedef const __attribute__((address_space(1))) void* gas_t;
typedef __attribute__((address_space(3))) void* las_t;

__device__ __forceinline__ short f2bf(float f) {
  union { float f; unsigned u; } v{f};
  unsigned r = (v.u + 0x7FFF + ((v.u >> 16) & 1)) >> 16;
  return (short)r;
}

__device__ __forceinline__ unsigned cvtpk_bf16(float lo, float hi) {
  unsigned r;
  asm("v_cvt_pk_bf16_f32 %0, %1, %2" : "=v"(r) : "v"(lo), "v"(hi));
  return r;
}

// exchange a's hi-32-lane values with b's lo-32-lane values (permlane32_swap
// semantics, emulated with one shfl_xor + selects for safety)
__device__ __forceinline__ void half_swap(unsigned& a, unsigned& b, bool ishi) {
  const unsigned sel = ishi ? a : b;
  const unsigned got = (unsigned)__shfl_xor((int)sel, 32, 64);
  a = ishi ? got : a;
  b = ishi ? b : got;
}

// ---------------- LayerNorm: one 256-thread block per row of 1024 ----------------
template <typename OT>
__global__ __launch_bounds__(256) void ln_kernel(
    const float* __restrict__ in, const float* __restrict__ w,
    const float* __restrict__ b, OT* __restrict__ out) {
  const int row = blockIdx.x;
  const int tid = threadIdx.x;
  const float4 v = ((const float4*)(in + (size_t)row * kD))[tid];
  float sum = v.x + v.y + v.z + v.w;
  float sq = v.x * v.x + v.y * v.y + v.z * v.z + v.w * v.w;
#pragma unroll
  for (int off = 32; off > 0; off >>= 1) {
    sum += __shfl_down(sum, off);
    sq += __shfl_down(sq, off);
  }
  __shared__ float s1[4], s2[4];
  const int wave = tid >> 6, lane = tid & 63;
  if (lane == 0) { s1[wave] = sum; s2[wave] = sq; }
  __syncthreads();
  const float ts = s1[0] + s1[1] + s1[2] + s1[3];
  const float tq = s2[0] + s2[1] + s2[2] + s2[3];
  const float mean = ts * (1.0f / kD);
  const float var = tq * (1.0f / kD) - mean * mean;
  const float rs = rsqrtf(var + kEps);
  const float4 w4 = ((const float4*)w)[tid];
  const float4 b4 = ((const float4*)b)[tid];
  float4 o;
  o.x = (v.x - mean) * rs * w4.x + b4.x;
  o.y = (v.y - mean) * rs * w4.y + b4.y;
  o.z = (v.z - mean) * rs * w4.z + b4.z;
  o.w = (v.w - mean) * rs * w4.w + b4.w;
  if constexpr (sizeof(OT) == 4) {
    ((float4*)(out + (size_t)row * kD))[tid] = o;
  } else {
    short4 s4;
    s4.x = f2bf(o.x); s4.y = f2bf(o.y); s4.z = f2bf(o.z); s4.w = f2bf(o.w);
    ((short4*)(out + (size_t)row * kD))[tid] = s4;
  }
}

// ------------- per-layer weight convert+transpose: fp32 [K,N] -> bf16 [N,K] -----
__global__ __launch_bounds__(256) void convT_kernel(
    const float* __restrict__ aw, const float* __restrict__ pw,
    const float* __restrict__ fw, const float* __restrict__ gw,
    short* __restrict__ awT, short* __restrict__ pwT,
    short* __restrict__ fwT, short* __restrict__ gwT) {
  __shared__ short t[64][66];
  int b = blockIdx.x;
  const float* src; short* dst; int K, N, tk, tn;
  if (b < 768)       { src = aw; dst = awT; K = 1024; N = 3072; tk = b / 48; tn = b % 48; }
  else if (b < 1024) { b -= 768;  src = pw; dst = pwT; K = 1024; N = 1024; tk = b / 16; tn = b % 16; }
  else if (b < 2048) { b -= 1024; src = fw; dst = fwT; K = 1024; N = 4096; tk = b / 64; tn = b % 64; }
  else               { b -= 2048; src = gw; dst = gwT; K = 4096; N = 1024; tk = b / 16; tn = b % 16; }
  const int k0 = tk * 64, n0 = tn * 64;
  const int tr = threadIdx.x >> 4, tc4 = (threadIdx.x & 15) << 2;
#pragma unroll
  for (int i = 0; i < 4; ++i) {
    const int k = tr + i * 16;
    const float4 v = *(const float4*)(src + (size_t)(k0 + k) * N + n0 + tc4);
    t[k][tc4 + 0] = f2bf(v.x); t[k][tc4 + 1] = f2bf(v.y);
    t[k][tc4 + 2] = f2bf(v.z); t[k][tc4 + 3] = f2bf(v.w);
  }
  __syncthreads();
#pragma unroll
  for (int i = 0; i < 4; ++i) {
    const int n = tr + i * 16;
    short4 o;
    o.x = t[tc4 + 0][n]; o.y = t[tc4 + 1][n];
    o.z = t[tc4 + 2][n]; o.w = t[tc4 + 3][n];
    *(short4*)(dst + (size_t)(n0 + n) * K + k0 + tc4) = o;
  }
}

// ---------------- bf16 MFMA GEMM: C[M,N] = A[M,K]·B^T[N,K]^T + bias -------------
template <int OUT, bool RELU>
__global__ __launch_bounds__(256) void mfma_gemm(
    const short* __restrict__ A, const short* __restrict__ BT,
    const float* __restrict__ bias, const float* __restrict__ res,
    void* __restrict__ Cout, int N, int K) {
  __shared__ __align__(16) short As[128 * 64];
  __shared__ __align__(16) short Bs[128 * 64];
  const int tid = threadIdx.x;
  const int w = tid >> 6, lane = tid & 63;
  const int n16 = lane & 15, quad = lane >> 4;
  const int m0 = blockIdx.y * 128, n0 = blockIdx.x * 128;
  const int wr = (w >> 1) * 64, wc = (w & 1) * 64;

  f32x4 acc[4][4];
#pragma unroll
  for (int i = 0; i < 4; ++i)
#pragma unroll
    for (int j = 0; j < 4; ++j) acc[i][j] = (f32x4)0.f;

  const int srow = lane >> 3;
  const int schunk = lane & 7;

  for (int k0 = 0; k0 < K; k0 += 64) {
#pragma unroll
    for (int s = 0; s < 4; ++s) {
      const int r = (w * 4 + s) * 8 + srow;
      const int cs = schunk ^ (r & 7);
      __builtin_amdgcn_global_load_lds(
          (gas_t)(const void*)(A + (size_t)(m0 + r) * K + k0 + cs * 8),
          (las_t)(void*)(As + (w * 4 + s) * 8 * 64), 16, 0, 0);
      __builtin_amdgcn_global_load_lds(
          (gas_t)(const void*)(BT + (size_t)(n0 + r) * K + k0 + cs * 8),
          (las_t)(void*)(Bs + (w * 4 + s) * 8 * 64), 16, 0, 0);
    }
    __syncthreads();
#pragma unroll
    for (int kc = 0; kc < 2; ++kc) {
      bf16x8 af[4], bfr[4];
#pragma unroll
      for (int i = 0; i < 4; ++i) {
        const int m = wr + i * 16 + n16;
        af[i] = *(const bf16x8*)(As + m * 64 + (((kc << 2) + quad) ^ (m & 7)) * 8);
        const int n = wc + i * 16 + n16;
        bfr[i] = *(const bf16x8*)(Bs + n * 64 + (((kc << 2) + quad) ^ (n & 7)) * 8);
      }
#pragma unroll
      for (int i = 0; i < 4; ++i)
#pragma unroll
        for (int j = 0; j < 4; ++j)
          acc[i][j] = __builtin_amdgcn_mfma_f32_16x16x32_bf16(af[i], bfr[j],
                                                              acc[i][j], 0, 0, 0);
    }
    __syncthreads();
  }

#pragma unroll
  for (int j = 0; j < 4; ++j) {
    const int n = n0 + wc + j * 16 + n16;
    const float bv = bias[n];
#pragma unroll
    for (int i = 0; i < 4; ++i) {
#pragma unroll
      for (int r = 0; r < 4; ++r) {
        const int m = m0 + wr + i * 16 + quad * 4 + r;
        float v = acc[i][j][r] + bv;
        if (OUT == 1) {
          ((float*)Cout)[(size_t)m * N + n] = v + res[(size_t)m * N + n];
        } else {
          if (RELU) v = fmaxf(v, 0.f);
          ((short*)Cout)[(size_t)m * N + n] = f2bf(v);
        }
      }
    }
  }
}

// ---------------- MFMA bf16 flash attention, swapped-QK 32x32 structure ---------
// Block: one (b,h) x 128 q rows; 4 waves, wave w owns q rows qw0..qw0+31 with
// q = lane&31 (both lane halves). KVBLK=64, double-buffered K/V staging via
// global_load_lds. QK^T computed swapped (A=K, B=Q) -> St[k][q]: softmax is
// in-lane + one shfl_xor(32). P packed to bf16 via v_cvt_pk + lane-half swap.
// PV computes O^T (A=V^T via ds_read_b64_tr_b16 from subtiled LDS, B=P) so the
// accumulator keeps q = lane&31 ownership (in-lane rescale).
__global__ __launch_bounds__(256) void attn_kernel(
    const short* __restrict__ qkv, const float* __restrict__ amaskp,
    short* __restrict__ ctx) {
  // per buffer: K [64 keys][64 d] chunk-swizzled (8KB) | V subtiled [16][4][4][16] (8KB)
  __shared__ __align__(16) short smem[2][8192];

  const int tid = threadIdx.x;
  const int w = tid >> 6;
  const int lane = tid & 63;
  const int l31 = lane & 31;
  const int hi = lane >> 5;
  const int bh = blockIdx.x;
  const int bb = bh >> 4, hh = bh & 15;
  const int qb = gridDim.y - 1 - blockIdx.y;  // heavy causal blocks first
  const int q0 = qb * 128;
  const int qw0 = q0 + w * 32;

  const short* base  = qkv + (size_t)bb * kT * 3072;
  const short* kbase = base + 1024 + hh * 64;
  const short* vbase = base + 2048 + hh * 64;
  const float* amp   = amaskp + bb * kT;

  // Q B-fragments (persistent): qf[mi] = Q[qw0+l31][16*mi + 8*hi + 0..7]
  bf16x8 qf[4];
  {
    const short* qp = base + (size_t)(qw0 + l31) * 3072 + hh * 64 + hi * 8;
#pragma unroll
    for (int mi = 0; mi < 4; ++mi) qf[mi] = *(const bf16x8*)(qp + mi * 16);
  }

  f32x16 O[2];
  O[0] = (f32x16)0.f;
  O[1] = (f32x16)0.f;
  float m_r = -1e30f, l_r = 0.f;

  // staging lane decomposition
  const int krow = tid >> 3, kch = tid & 7;                       // K stage
  const int vk4 = tid >> 5, vd16 = (tid >> 3) & 3;                // V stage
  const int vkin = (tid >> 1) & 3, vdh = tid & 1;
  const int wuni = (tid & 192) * 8;  // wave-uniform LDS short offset (HW adds lane*16B)

  // per-lane tr-read base (byte offset into LDS): group g = lane>>4 reads
  // subtile [4k][16d]; kk4 contribution 2*(g>>1), d16 contribution (g&1)
  const unsigned vs0 = (unsigned)(size_t)(las_t)(void*)(&smem[0][4096]);
  const int g = lane >> 4;
  const unsigned vtr =
      vs0 + (unsigned)((g >> 1) * 1024 + (g & 1) * 128 + (lane & 15) * 8);

  auto STAGE = [&](int buf, int k0) {
    short* ks = &smem[buf][0];
    short* vs = &smem[buf][4096];
#pragma unroll
    for (int r2 = 0; r2 < 2; ++r2) {
      const int rr = r2 * 32 + krow;
      __builtin_amdgcn_global_load_lds(
          (gas_t)(const void*)(kbase + (size_t)(k0 + rr) * 3072 +
                               ((kch ^ (rr & 7)) << 3)),
          (las_t)(void*)(ks + r2 * 2048 + wuni), 16, 0, 0);
      const int key = k0 + r2 * 32 + vk4 * 4 + vkin;
      __builtin_amdgcn_global_load_lds(
          (gas_t)(const void*)(vbase + (size_t)key * 3072 + vd16 * 16 + vdh * 8),
          (las_t)(void*)(vs + r2 * 2048 + wuni), 16, 0, 0);
    }
  };

  const int kend = q0 + 128;
  STAGE(0, 0);
  __syncthreads();
  int cur = 0;

  for (int k0 = 0; k0 < kend; k0 += 64) {
    if (k0 + 64 < kend) STAGE(cur ^ 1, k0 + 64);

    if (k0 <= qw0 + 31) {  // wave has at least one unmasked key in this tile
      const short* ks = &smem[cur][0];

      // ---- St = K · Q^T  (St[key][q], col = q = lane&31) ----
      f32x16 st[2];
      st[0] = (f32x16)0.f;
      st[1] = (f32x16)0.f;
#pragma unroll
      for (int s = 0; s < 2; ++s) {
        const int row = s * 32 + l31;
        const short* kp = ks + row * 64;
#pragma unroll
        for (int mi = 0; mi < 4; ++mi) {
          const bf16x8 kf =
              *(const bf16x8*)(kp + (((2 * mi + hi) ^ (row & 7)) << 3));
          st[s] = __builtin_amdgcn_mfma_f32_32x32x16_bf16(kf, qf[mi], st[s],
                                                          0, 0, 0);
        }
      }

      // ---- scale + causal mask + additive attention mask ----
#pragma unroll
      for (int s = 0; s < 2; ++s) {
        const bool pm = (k0 + 32 * s + 31 > qw0);
#pragma unroll
        for (int rq = 0; rq < 4; ++rq) {
          const int kb_ = k0 + 32 * s + 8 * rq + 4 * hi;
          const float4 a4 = *(const float4*)(amp + kb_);
          const float amv0 = (1.f - a4.x) * -10000.f;
          const float amv1 = (1.f - a4.y) * -10000.f;
          const float amv2 = (1.f - a4.z) * -10000.f;
          const float amv3 = (1.f - a4.w) * -10000.f;
          float v0 = st[s][rq * 4 + 0] * 0.125f;
          float v1 = st[s][rq * 4 + 1] * 0.125f;
          float v2 = st[s][rq * 4 + 2] * 0.125f;
          float v3 = st[s][rq * 4 + 3] * 0.125f;
          if (pm) {
            const int q = qw0 + l31;
            if (kb_ + 0 > q) v0 = -10000.f;
            if (kb_ + 1 > q) v1 = -10000.f;
            if (kb_ + 2 > q) v2 = -10000.f;
            if (kb_ + 3 > q) v3 = -10000.f;
          }
          st[s][rq * 4 + 0] = v0 + amv0;
          st[s][rq * 4 + 1] = v1 + amv1;
          st[s][rq * 4 + 2] = v2 + amv2;
          st[s][rq * 4 + 3] = v3 + amv3;
        }
      }

      // ---- online softmax (in-lane over 32 + one cross-half shfl) ----
      float mx = st[0][0];
#pragma unroll
      for (int r = 1; r < 16; ++r) mx = fmaxf(mx, st[0][r]);
#pragma unroll
      for (int r = 0; r < 16; ++r) mx = fmaxf(mx, st[1][r]);
      mx = fmaxf(mx, __shfl_xor(mx, 32, 64));
      const float mn = fmaxf(m_r, mx);
      const float al = __expf(m_r - mn);
      m_r = mn;
      float sum = 0.f;
#pragma unroll
      for (int s = 0; s < 2; ++s)
#pragma unroll
        for (int r = 0; r < 16; ++r) {
          const float p = __expf(st[s][r] - mn);
          st[s][r] = p;
          sum += p;
        }
      sum += __shfl_xor(sum, 32, 64);
      l_r = l_r * al + sum;
#pragma unroll
      for (int r = 0; r < 16; ++r) {
        O[0][r] *= al;
        O[1][r] *= al;
      }

      // ---- pack P -> bf16 B-fragments (cvt_pk + lane-half swap) ----
      bf16x8 pf[4];
      const bool ishi = (hi != 0);
#pragma unroll
      for (int s = 0; s < 2; ++s) {
#pragma unroll
        for (int hf = 0; hf < 2; ++hf) {
          unsigned wa = cvtpk_bf16(st[s][8 * hf + 0], st[s][8 * hf + 1]);
          unsigned wc = cvtpk_bf16(st[s][8 * hf + 4], st[s][8 * hf + 5]);
          half_swap(wa, wc, ishi);
          unsigned wb = cvtpk_bf16(st[s][8 * hf + 2], st[s][8 * hf + 3]);
          unsigned wd = cvtpk_bf16(st[s][8 * hf + 6], st[s][8 * hf + 7]);
          half_swap(wb, wd, ishi);
          union { unsigned u[4]; bf16x8 h; } f;
          f.u[0] = wa; f.u[1] = wb; f.u[2] = wc; f.u[3] = wd;
          pf[s * 2 + hf] = f.h;
        }
      }

      // ---- O^T += V^T · P  (V^T A-frags via hardware transpose read) ----
      unsigned long long tv[16];
      const unsigned vb_ = vtr + (unsigned)(cur << 14);
#pragma unroll
      for (int c = 0; c < 4; ++c)
#pragma unroll
        for (int di = 0; di < 2; ++di) {
          asm volatile("ds_read_b64_tr_b16 %0, %1 offset:%2"
                       : "=v"(tv[(c * 2 + di) * 2 + 0])
                       : "v"(vb_), "n"(c * 2048 + di * 256));
          asm volatile("ds_read_b64_tr_b16 %0, %1 offset:%2"
                       : "=v"(tv[(c * 2 + di) * 2 + 1])
                       : "v"(vb_), "n"(c * 2048 + di * 256 + 512));
        }
      asm volatile("s_waitcnt lgkmcnt(0)" ::: "memory");
      __builtin_amdgcn_sched_barrier(0);
#pragma unroll
      for (int c = 0; c < 4; ++c)
#pragma unroll
        for (int di = 0; di < 2; ++di) {
          union { unsigned long long q[2]; bf16x8 h; } vf_;
          vf_.q[0] = tv[(c * 2 + di) * 2 + 0];
          vf_.q[1] = tv[(c * 2 + di) * 2 + 1];
          O[di] = __builtin_amdgcn_mfma_f32_32x32x16_bf16(vf_.h, pf[c], O[di],
                                                          0, 0, 0);
        }
    }

    __syncthreads();
    cur ^= 1;
  }

  // ---- epilogue: ctx bf16; lane owns q = qw0+l31, regs span dims ----
  const float inv = 1.f / l_r;
  const size_t tok = (size_t)bb * kT + qw0 + l31;
  short* cp = ctx + tok * 1024 + hh * 64 + 4 * hi;
#pragma unroll
  for (int di = 0; di < 2; ++di)
#pragma unroll
    for (int rq = 0; rq < 4; ++rq) {
      short4 o4;
      o4.x = f2bf(O[di][rq * 4 + 0] * inv);
      o4.y = f2bf(O[di][rq * 4 + 1] * inv);
      o4.z = f2bf(O[di][rq * 4 + 2] * inv);
      o4.w = f2bf(O[di][rq * 4 + 3] * inv);
      *(short4*)(cp + di * 32 + rq * 8) = o4;
    }
}

// --------------------------------- launcher -------------------------------------
extern "C" void kernel_launch(void* const* d_in, const int* in_sizes, int n_in,
                              void* d_out, int out_size, void* d_ws, size_t ws_size,
                              hipStream_t stream) {
  const float* emb   = (const float*)d_in[0];
  const float* amask = (const float*)d_in[1];
  const float* ln1w  = (const float*)d_in[2];
  const float* ln1b  = (const float*)d_in[3];
  const float* attnw = (const float*)d_in[4];
  const float* attnb = (const float*)d_in[5];
  const float* projw = (const float*)d_in[6];
  const float* projb = (const float*)d_in[7];
  const float* ln2w  = (const float*)d_in[8];
  const float* ln2b  = (const float*)d_in[9];
  const float* fcw   = (const float*)d_in[10];
  const float* fcb   = (const float*)d_in[11];
  const float* fcpw  = (const float*)d_in[12];
  const float* fcpb  = (const float*)d_in[13];
  const float* lnfw  = (const float*)d_in[14];
  const float* lnfb  = (const float*)d_in[15];
  float* out = (float*)d_out;

  float* h    = (float*)d_ws;                          // 4096x1024 fp32
  short* xb   = (short*)(h + (size_t)kM * kD);         // 4096x1024 bf16
  short* ctxb = xb + (size_t)kM * kD;                  // 4096x1024 bf16
  short* bigb = ctxb + (size_t)kM * kD;                // 4096x4096 bf16 (qkv/ffn)
  short* awT  = bigb + (size_t)kM * kInner;            // 3072x1024
  short* pwT  = awT + (size_t)3072 * 1024;             // 1024x1024
  short* fwT  = pwT + (size_t)1024 * 1024;             // 4096x1024
  short* gwT  = fwT + (size_t)4096 * 1024;             // 1024x4096

  hipMemcpyAsync(h, emb, sizeof(float) * (size_t)kM * kD,
                 hipMemcpyDeviceToDevice, stream);

  const dim3 blk(256);
  for (int l = 0; l < kL; ++l) {
    convT_kernel<<<3072, blk, 0, stream>>>(
        attnw + (size_t)l * kD * 3072, projw + (size_t)l * kD * kD,
        fcw + (size_t)l * kD * kInner, fcpw + (size_t)l * kInner * kD,
        awT, pwT, fwT, gwT);
    ln_kernel<short><<<kM, blk, 0, stream>>>(h, ln1w + l * kD, ln1b + l * kD, xb);
    mfma_gemm<0, false><<<dim3(3072 / 128, kM / 128), blk, 0, stream>>>(
        xb, awT, attnb + l * 3072, nullptr, bigb, 3072, 1024);
    attn_kernel<<<dim3(kB * kH, kT / 128), blk, 0, stream>>>(bigb, amask, ctxb);
    mfma_gemm<1, false><<<dim3(1024 / 128, kM / 128), blk, 0, stream>>>(
        ctxb, pwT, projb + l * kD, h, h, 1024, 1024);
    ln_kernel<short><<<kM, blk, 0, stream>>>(h, ln2w + l * kD, ln2b + l * kD, xb);
    mfma_gemm<0, true><<<dim3(4096 / 128, kM / 128), blk, 0, stream>>>(
        xb, fwT, fcb + l * kInner, nullptr, bigb, 4096, 1024);
    mfma_gemm<1, false><<<dim3(1024 / 128, kM / 128), blk, 0, stream>>>(
        bigb, gwT, fcpb + l * kD, h, h, 1024, 4096);
  }
  ln_kernel<float><<<kM, blk, 0, stream>>>(h, lnfw, lnfb, out);
}